// Round 10
// baseline (4033.973 us; speedup 1.0000x reference)
//
#include <hip/hip_runtime.h>
#include <cmath>

// Volume: [B=4, C=1, D=128, H=128, W=128] fp32
#define NB 4
#define ND 128
#define NH 128
#define NW 128
#define NVOL_VOX (ND * NH * NW)    // 2097152 per volume
#define NVOX (NB * NVOL_VOX)       // 8388608 (4 volumes)

#define THREADS 256
#define TX 32
#define TY 16
// Regime (rounds 0-9): no pipe saturated (DS ~59%, VALU ~50%, HBM 32%) at 2 blocks/CU.
// Bank-conflict counter = structural wave64 2-way aliasing (168/block-step exactly), not
// fixable. Occupancy knob history: hipcc VGPR budget = 512/(2*arg2): arg2=2 -> 128 (OK,
// kernel uses 112-116); arg2=4 -> 64 (1GB spill, R2); waves_per_eu(4,8) targets max ->
// 64 (R7). waves_per_eu(4,4): budget 128 = today's proven budget, occupancy target 4
// waves/EU = 4 blocks/CU. zc=4 -> 1024 blocks = exactly 4/CU.
#define SSTR 10
#define RSTR 10
#define ZS4 ((NH * NW) >> 2)       // 4096 f4 per z-slice

#define INFF __builtin_huge_valf()

// barrier that orders LDS only: do NOT drain vmcnt (global prefetches stay in flight)
#define LDS_BARRIER()  do {                                   \
    asm volatile("s_waitcnt lgkmcnt(0)" ::: "memory");        \
    __builtin_amdgcn_s_barrier();                             \
    __builtin_amdgcn_sched_barrier(0);                        \
} while (0)

__device__ __forceinline__ float4 f4min(float4 a, float4 b) {
    return make_float4(fminf(a.x, b.x), fminf(a.y, b.y), fminf(a.z, b.z), fminf(a.w, b.w));
}
__device__ __forceinline__ float4 f4max(float4 a, float4 b) {
    return make_float4(fmaxf(a.x, b.x), fmaxf(a.y, b.y), fmaxf(a.z, b.z), fmaxf(a.w, b.w));
}
__device__ __forceinline__ float4 f4relu_sub(float4 a, float4 b) {
    return make_float4(fmaxf(a.x - b.x, 0.f), fmaxf(a.y - b.y, 0.f),
                       fmaxf(a.z - b.z, 0.f), fmaxf(a.w - b.w, 0.f));
}
// x-window ops with scalar boundary floats
__device__ __forceinline__ float4 f4winmin_s(float lfw, float4 cc, float rtx) {
    float4 o;
    o.x = fminf(fminf(lfw, cc.x), cc.y);
    o.y = fminf(fminf(cc.x, cc.y), cc.z);
    o.z = fminf(fminf(cc.y, cc.z), cc.w);
    o.w = fminf(fminf(cc.z, cc.w), rtx);
    return o;
}
__device__ __forceinline__ float4 f4winmax_s(float lfw, float4 cc, float rtx) {
    float4 o;
    o.x = fmaxf(fmaxf(lfw, cc.x), cc.y);
    o.y = fmaxf(fmaxf(cc.x, cc.y), cc.z);
    o.z = fmaxf(fmaxf(cc.y, cc.z), cc.w);
    o.w = fmaxf(fmaxf(cc.z, cc.w), rtx);
    return o;
}

__device__ __forceinline__ float block_reduce(float v, float* sbuf) {
    for (int off = 32; off > 0; off >>= 1) v += __shfl_down(v, off, 64);
    int lane = threadIdx.x & 63;
    int wid  = threadIdx.x >> 6;
    if (lane == 0) sbuf[wid] = v;
    __syncthreads();
    float r = 0.f;
    if (wid == 0) {
        r = (lane < (int)(blockDim.x >> 6)) ? sbuf[lane] : 0.f;
        for (int off = 8; off > 0; off >>= 1) r += __shfl_down(r, off, 64);
    }
    __syncthreads();
    return r;
}

// ---------------------------------------------------------------------------
// sigmoid + dice partials
// ---------------------------------------------------------------------------
#define SIG_BLOCKS 1024
__global__ void sigmoid_reduce_kernel(const float4* __restrict__ logits,
                                      const float4* __restrict__ yt,
                                      float4* __restrict__ yp,
                                      float* __restrict__ part) {
    __shared__ float sbuf[THREADS / 64];
    const int n4 = NVOX / 4;
    float sp = 0.f, st = 0.f, stp = 0.f;
    for (int i = blockIdx.x * blockDim.x + threadIdx.x; i < n4;
         i += gridDim.x * blockDim.x) {
        float4 l = logits[i];
        float4 t = yt[i];
        float4 p;
        p.x = 1.f / (1.f + expf(-l.x));
        p.y = 1.f / (1.f + expf(-l.y));
        p.z = 1.f / (1.f + expf(-l.z));
        p.w = 1.f / (1.f + expf(-l.w));
        yp[i] = p;
        sp  += p.x + p.y + p.z + p.w;
        st  += t.x + t.y + t.z + t.w;
        stp += t.x * p.x + t.y * p.y + t.z * p.z + t.w * p.w;
    }
    float a = block_reduce(sp, sbuf);
    float b = block_reduce(st, sbuf);
    float c = block_reduce(stp, sbuf);
    if (threadIdx.x == 0) {
        part[blockIdx.x]        = a;
        part[1024 + blockIdx.x] = b;
        part[2048 + blockIdx.x] = c;
    }
}

// ---------------------------------------------------------------------------
// Fused skeleton kernel (pair of iterations; INIT also folds the init step).
// ---------------------------------------------------------------------------
template <int RED, int INIT>
__attribute__((amdgpu_waves_per_eu(4, 4)))
__global__ __launch_bounds__(256)
void skel_pair_kernel(const float* __restrict__ srcA, const float* __restrict__ srcB,
                      float* __restrict__ imgOut, float* __restrict__ skel,
                      int zchunks,
                      const float* __restrict__ othA, const float* __restrict__ othB,
                      float* __restrict__ part, int offBase) {
    // per-slice f4 counts (srcS removed: src neighbors come from global prefetch)
    constexpr int ZE1  = 22 * SSTR;
    constexpr int ZE2  = 20 * SSTR;
    constexpr int ZE3  = 18 * SSTR;
    constexpr int ZRX  = 18 * RSTR;
    // +2: one f4 pad at each end so the ±1-f4 halo reads stay inside smem
    constexpr int NTOT = 2 + 2 * (ZE1 + ZE2 + ZE3 + 2 * ZRX)
                           + (INIT ? 2 * ZRX : 0);
    __shared__ float4 smem[NTOT];
    float4* const e1S  = smem + 1;
    float4* const e2S  = e1S + 2 * ZE1;
    float4* const e3S  = e2S + 2 * ZE2;
    float4* const rxAS = e3S + 2 * ZE3;
    float4* const rxBS = rxAS + 2 * ZRX;
    float4* const rxCS = rxBS + 2 * ZRX;   // only valid for INIT

    const float4 INF4  = make_float4(INFF, INFF, INFF, INFF);
    const float4 MINF4 = make_float4(-INFF, -INFF, -INFF, -INFF);
    const float4 ZERO4 = make_float4(0.f, 0.f, 0.f, 0.f);

    const int zlen  = ND / zchunks;
    const int v     = blockIdx.z / zchunks;
    const int chunk = blockIdx.z - v * zchunks;
    const int z0    = chunk * zlen;
    const int tx0   = blockIdx.x * TX;
    const int ty0   = blockIdx.y * TY;
    const int tid   = threadIdx.x;

    const float* src = srcB ? (v < 4 ? srcA + (size_t)v * NVOL_VOX
                                     : srcB + (size_t)(v - 4) * NVOL_VOX)
                            : srcA + (size_t)v * NVOL_VOX;
    const float4* src4 = (const float4*)src;
    const float*  srcf = src;
    float4* img4 = imgOut ? (float4*)(imgOut + (size_t)v * NVOL_VOX) : nullptr;
    float4* skl4 = (float4*)(skel + (size_t)v * NVOL_VOX);
    const float4* oth4 = nullptr;
    if (RED) {
        const float* oth = othB ? (v < 4 ? othA + (size_t)v * NVOL_VOX
                                         : othB + (size_t)(v - 4) * NVOL_VOX)
                                : othA + (size_t)v * NVOL_VOX;
        oth4 = (const float4*)oth;
    }

    const int fy = tid / 10, qx = tid - (tid / 10) * 10;   // rows 0..23, cols 0..9
    const bool tOK = tid < 240;
    const bool aE1 = tOK && fy >= 1 && fy < 23;
    const bool aE2 = tOK && fy >= 2 && fy < 22;
    const bool aE3 = tOK && fy >= 3 && fy < 21;
    const bool aRx = aE3 && qx >= 1 && qx < 9;
    const bool aC  = tOK && fy >= 4 && fy < 20 && qx >= 1 && qx < 9;
    const bool qxL = (qx == 0);
    const bool qxR = (qx == 9);
    const int gy = ty0 + fy - 4;
    const int gx4 = tx0 + (qx - 1) * 4;
    const bool xOK = tOK && (unsigned)gx4 < NW;
    const bool gOK = xOK && (unsigned)gy < NH;
    const bool upOK = xOK && (unsigned)(gy - 1) < NH;
    const bool dnOK = xOK && (unsigned)(gy + 1) < NH;
    const bool lfOK = gOK && !qxL && (gx4 - 1) >= 0;
    const bool rtOK = gOK && !qxR && (gx4 + 4) < NW;
    const int colBase = gOK ? ((gy * NW + gx4) >> 2) : 0;
    const int colUp   = upOK ? (((gy - 1) * NW + gx4) >> 2) : 0;
    const int colDn   = dnOK ? (((gy + 1) * NW + gx4) >> 2) : 0;
    const int lfIdx   = lfOK ? (gy * NW + gx4 - 1) : 0;
    const int rtIdx   = rtOK ? (gy * NW + gx4 + 4) : 0;
    const int iE1  = (fy - 1) * SSTR + qx;
    const int iE2  = (fy - 2) * SSTR + qx;
    const int iE3  = (fy - 3) * SSTR + qx;
    const int iRx  = (fy - 3) * RSTR + (qx - 1);

    // src register rotation (6 deep): srcF[(u+1)%6]=zL+1 (prefetch), [u%6]=zL,
    // [(u+5)%6]=zL-1, [(u+4)%6]=zL-2, [(u+2)%6]=zL-4 (INIT d0).
    // y-neighbor/x-halo prefetch (3 deep): write slot (u+1)%3 (slice zL+1),
    // consume slot (u+2)%3 (slice zL-1) in E1.
    float4 srcF[6], yupF[3], ydnF[3];
    float  lfwF[3], rtxF[3];
    float4 e1F[6], e2F[6], e3F[2], rxAF[2], rxBF[2], mxyAF[3], mxyBF[3], dAF[2];
    float4 sklF[6], othF[6];
    float4 rxCF[2], mxyCF[3], d0F[3];
#pragma unroll
    for (int i = 0; i < 6; ++i) srcF[i] = INF4;
#pragma unroll
    for (int i = 0; i < 3; ++i) { yupF[i] = INF4; ydnF[i] = INF4; lfwF[i] = INFF; rtxF[i] = INFF; }
#pragma unroll
    for (int i = 0; i < 6; ++i) { e1F[i] = INF4; e2F[i] = INF4; sklF[i] = ZERO4; othF[i] = ZERO4; }
    e3F[0] = e3F[1] = INF4;
    rxAF[0] = rxAF[1] = MINF4;
    rxBF[0] = rxBF[1] = MINF4;
    rxCF[0] = rxCF[1] = MINF4;
    mxyAF[0] = mxyAF[1] = mxyAF[2] = MINF4;
    mxyBF[0] = mxyBF[1] = mxyBF[2] = MINF4;
    mxyCF[0] = mxyCF[1] = mxyCF[2] = MINF4;
    dAF[0] = dAF[1] = ZERO4;
    d0F[0] = d0F[1] = d0F[2] = ZERO4;

    float accS = 0.f, accSO = 0.f;
    const int NSTEP = zlen + 10;

    {   // prologue: own slice z0-4 -> srcF[0]; neighbor slices z0-5 -> slot 2,
        // z0-4 -> slot 0 (consumed by E1 at steps 0,1)
        const int zB = z0 - 4, zA = z0 - 5;
        if ((unsigned)zB < ND && gOK) srcF[0] = src4[zB * ZS4 + colBase];
        if ((unsigned)zA < ND) {
            if (upOK) yupF[2] = src4[zA * ZS4 + colUp];
            if (dnOK) ydnF[2] = src4[zA * ZS4 + colDn];
            if (lfOK) lfwF[2] = srcf[zA * (NH * NW) + lfIdx];
            if (rtOK) rtxF[2] = srcf[zA * (NH * NW) + rtIdx];
        }
        if ((unsigned)zB < ND) {
            if (upOK) yupF[0] = src4[zB * ZS4 + colUp];
            if (dnOK) ydnF[0] = src4[zB * ZS4 + colDn];
            if (lfOK) lfwF[0] = srcf[zB * (NH * NW) + lfIdx];
            if (rtOK) rtxF[0] = srcf[zB * (NH * NW) + rtIdx];
        }
    }

    for (int sb = 0; sb < NSTEP; sb += 6) {
#pragma unroll
        for (int u = 0; u < 6; ++u) {
            if (sb + u >= NSTEP) break;            // uniform exit at exact step count
            const int zL = z0 - 4 + (sb + u);
            const int sl  = u & 1;
            const int slp = sl ^ 1;

            {   // prefetch slice zL+1: own f4 + y-neighbor f4s + x-halo scalars
                const int zN = zL + 1;
                const bool zOK = (unsigned)zN < ND && zN < z0 + zlen + 4;
                float4 vv = INF4, vu = INF4, vd = INF4;
                float lf = INFF, rt = INFF;
                if (zOK) {
                    if (gOK)  vv = src4[zN * ZS4 + colBase];
                    if (upOK) vu = src4[zN * ZS4 + colUp];
                    if (dnOK) vd = src4[zN * ZS4 + colDn];
                    if (lfOK) lf = srcf[zN * (NH * NW) + lfIdx];
                    if (rtOK) rt = srcf[zN * (NH * NW) + rtIdx];
                }
                srcF[(u + 1) % 6] = vv;
                yupF[(u + 1) % 3] = vu;
                ydnF[(u + 1) % 3] = vd;
                lfwF[(u + 1) % 3] = lf;
                rtxF[(u + 1) % 3] = rt;
            }
            if (!INIT) {   // prefetch skel/oth for OUT 3 steps ahead (z = zL-3)
                const int zp = zL - 3;
                const bool pOK = aC && zp >= z0 && zp < z0 + zlen;
                float4 sv = ZERO4;
                if (pOK) sv = skl4[zp * ZS4 + colBase];
                sklF[u] = sv;
                if (RED) {
                    float4 ov = ZERO4;
                    if (pOK) ov = oth4[zp * ZS4 + colBase];
                    othF[u] = ov;
                }
            }
            {   // E1(zL-1) — all inputs from registers (prefetched 2 steps ago)
                const int z = zL - 1;
                float4 vv = INF4;
                if (aE1 && (unsigned)z < ND) {
                    float4 cc = srcF[(u + 5) % 6];                       // zL-1
                    float4 zm = f4min(srcF[(u + 4) % 6], srcF[u % 6]);   // zL-2, zL
                    float lfw = qxL ? INFF : lfwF[(u + 2) % 3];
                    float rtx = qxR ? INFF : rtxF[(u + 2) % 3];
                    float4 xm = f4winmin_s(lfw, cc, rtx);
                    vv = f4min(f4min(xm, yupF[(u + 2) % 3]),
                               f4min(ydnF[(u + 2) % 3], zm));
                }
                e1F[u % 6] = vv;
                if (aE1) e1S[sl * ZE1 + iE1] = vv;
            }
            {   // E2(zL-2) — img output  (x-halo via neighbor-f4 b128)
                const int z = zL - 2;
                float4 vv = INF4;
                if (aE2) {
                    const float4* S = e1S + slp * ZE1;
                    float4 lf4 = S[iE1 - 1];
                    float4 rt4 = S[iE1 + 1];
                    float lfw = qxL ? INFF : lf4.w;
                    float rtx = qxR ? INFF : rt4.x;
                    float4 xm = f4winmin_s(lfw, e1F[(u + 5) % 6], rtx);
                    vv = f4min(f4min(xm, S[iE1 - SSTR]),
                               f4min(S[iE1 + SSTR],
                                     f4min(e1F[(u + 4) % 6], e1F[u % 6])));
                    e2S[sl * ZE2 + iE2] = vv;
                    if (img4 && aC && z >= z0 && z < z0 + zlen)
                        img4[z * ZS4 + colBase] = vv;
                }
                e2F[u % 6] = vv;
            }
            {   // E3(zL-3)  (x-halo via neighbor-f4 b128)
                float4 vv = INF4;
                if (aE3) {
                    const float4* S = e2S + slp * ZE2;
                    float4 lf4 = S[iE2 - 1];
                    float4 rt4 = S[iE2 + 1];
                    float lfw = qxL ? INFF : lf4.w;
                    float rtx = qxR ? INFF : rt4.x;
                    float4 xm = f4winmin_s(lfw, e2F[(u + 5) % 6], rtx);
                    vv = f4min(f4min(xm, S[iE2 - SSTR]),
                               f4min(S[iE2 + SSTR],
                                     f4min(e2F[(u + 4) % 6], e2F[u % 6])));
                    e3S[sl * ZE3 + iE3] = vv;
                }
                e3F[u % 2] = vv;
            }
            {   // rxA(zL-3), rxB(zL-4), [INIT] rxC(zL-2)  (halos via neighbor-f4 b128)
                float4 ra = MINF4, rb = MINF4, rc = MINF4;
                if (aRx) {
                    const float4* A4 = e2S + slp * ZE2;
                    const float4* B4 = e3S + slp * ZE3;
                    float4 aL = A4[iE2 - 1], aR = A4[iE2 + 1];
                    float4 bL = B4[iE3 - 1], bR = B4[iE3 + 1];
                    ra = f4winmax_s(aL.w, e2F[(u + 5) % 6], aR.x);
                    rb = f4winmax_s(bL.w, e3F[(u + 1) % 2], bR.x);
                    rxAS[sl * ZRX + iRx] = ra;
                    rxBS[sl * ZRX + iRx] = rb;
                    if (INIT) {
                        const float4* C4 = e1S + slp * ZE1;
                        float4 cL = C4[iE1 - 1], cR = C4[iE1 + 1];
                        rc = f4winmax_s(cL.w, e1F[(u + 5) % 6], cR.x);
                        rxCS[sl * ZRX + iRx] = rc;
                    }
                }
                float4 mA = MINF4, mB = MINF4, mC = MINF4;
                if (aC) {
                    mA = f4max(f4max(rxAF[(u + 1) % 2], rxAS[slp * ZRX + iRx - RSTR]),
                               rxAS[slp * ZRX + iRx + RSTR]);
                    mB = f4max(f4max(rxBF[(u + 1) % 2], rxBS[slp * ZRX + iRx - RSTR]),
                               rxBS[slp * ZRX + iRx + RSTR]);
                    if (INIT)
                        mC = f4max(f4max(rxCF[(u + 1) % 2], rxCS[slp * ZRX + iRx - RSTR]),
                                   rxCS[slp * ZRX + iRx + RSTR]);
                }
                rxAF[u % 2] = ra;
                rxBF[u % 2] = rb;
                mxyAF[u % 3] = mA;
                mxyBF[u % 3] = mB;
                if (INIT) { rxCF[u % 2] = rc; mxyCF[u % 3] = mC; }
            }
            if (INIT) {   // d0(zL-4) = relu(src(zL-4) - dilate(E1)(zL-4))
                float4 dilC = f4max(f4max(mxyCF[0], mxyCF[1]), mxyCF[2]);
                d0F[u % 3] = f4relu_sub(srcF[(u + 2) % 6], dilC);
            }
            {   // dA(zL-5) = relu(E1(zL-5) - dilA)
                float4 dilA = f4max(f4max(mxyAF[0], mxyAF[1]), mxyAF[2]);
                dAF[u % 2] = f4relu_sub(e1F[(u + 2) % 6], dilA);
            }
            {   // OUT(zL-6)
                const int z = zL - 6;
                if (aC && z >= z0 && z < z0 + zlen) {
                    float4 dilB = f4max(f4max(mxyBF[0], mxyBF[1]), mxyBF[2]);
                    float4 dB = f4relu_sub(e2F[(u + 2) % 6], dilB);
                    float4 da = dAF[(u + 1) % 2];
                    int gi = z * ZS4 + colBase;
                    float4 sv = INIT ? d0F[(u + 1) % 3] : sklF[(u + 3) % 6];
                    float4 s1, s2;
                    s1.x = sv.x + fmaxf(da.x - sv.x * da.x, 0.f);
                    s1.y = sv.y + fmaxf(da.y - sv.y * da.y, 0.f);
                    s1.z = sv.z + fmaxf(da.z - sv.z * da.z, 0.f);
                    s1.w = sv.w + fmaxf(da.w - sv.w * da.w, 0.f);
                    s2.x = s1.x + fmaxf(dB.x - s1.x * dB.x, 0.f);
                    s2.y = s1.y + fmaxf(dB.y - s1.y * dB.y, 0.f);
                    s2.z = s1.z + fmaxf(dB.z - s1.z * dB.z, 0.f);
                    s2.w = s1.w + fmaxf(dB.w - s1.w * dB.w, 0.f);
                    skl4[gi] = s2;
                    if (RED) {
                        accS += s2.x + s2.y + s2.z + s2.w;
                        float4 o = othF[(u + 3) % 6];
                        accSO += s2.x * o.x + s2.y * o.y + s2.z * o.z + s2.w * o.w;
                    }
                }
            }
            LDS_BARRIER();   // raw s_barrier + lgkmcnt(0); global prefetches stay in flight
        }
    }

    if (RED) {
        float* sbuf = (float*)smem;
        float r1 = block_reduce(accS, sbuf);
        float r2 = block_reduce(accSO, sbuf);
        if (tid == 0) {
            int halfSel = (othB && v >= 4) ? 1 : 0;
            int A = (offBase + 2 * halfSel) * 1024;
            int zslot = chunk + zchunks * (v & 3);
            int bid = blockIdx.x + 4 * (blockIdx.y + 8 * zslot);
            part[A + bid] = r1;
            part[A + 1024 + bid] = r2;
        }
    }
}

// ---------------------------------------------------------------------------
// finalize: sum 7 partial arrays (1024 each) and compute the loss scalar
// ---------------------------------------------------------------------------
__global__ void finalize_kernel(const float* __restrict__ part, float* __restrict__ out) {
    __shared__ float sbuf[THREADS / 64];
    float s[7];
#pragma unroll
    for (int k = 0; k < 7; ++k) {
        float local = 0.f;
        for (int i = threadIdx.x; i < 1024; i += THREADS) local += part[k * 1024 + i];
        s[k] = block_reduce(local, sbuf);
    }
    if (threadIdx.x == 0) {
        const float smooth = 1.0f;
        const float alpha = 0.3f;
        float dice = 1.f - (2.f * s[2] + smooth) / (s[1] + s[0] + smooth);
        float tprec = (s[4] + smooth) / (s[3] + smooth);
        float tsens = (s[6] + smooth) / (s[5] + smooth);
        float cl = 1.f - 2.f * (tprec * tsens) / (tprec + tsens);
        out[0] = (1.f - alpha) * dice + alpha * cl;
    }
}

// ---------------------------------------------------------------------------
extern "C" void kernel_launch(void* const* d_in, const int* in_sizes, int n_in,
                              void* d_out, int out_size, void* d_ws, size_t ws_size,
                              hipStream_t stream) {
    const float* y_pred = (const float*)d_in[0];
    const float* y_true = (const float*)d_in[1];
    float* out = (float*)d_out;

    char* ws = (char*)d_ws;
    float* part = (float*)ws;                 // 7 * 1024 floats
    float* yp = (float*)(ws + 32768);
    const size_t NB4 = (size_t)NVOX;
    const size_t need_batched = 32768 + 7 * NB4 * sizeof(float);

    hipMemsetAsync(part, 0, 7 * 1024 * sizeof(float), stream);
    sigmoid_reduce_kernel<<<SIG_BLOCKS, THREADS, 0, stream>>>(
        (const float4*)y_pred, (const float4*)y_true, (float4*)yp, part);

    if (ws_size >= need_batched) {
        // batched: both skeletons (8 volumes) per dispatch
        float* ping = yp + NB4;          // 8-vol
        float* pong = ping + 2 * NB4;    // 8-vol
        float* S    = pong + 2 * NB4;    // 8-vol
        const int zc = 4;                // zlen 32 -> 1024 blocks = exactly 4 blocks/CU
        dim3 grid(NW / TX, NH / TY, zc * 8);   // 4 x 8 x 32 = 1024

        // init + iters 1-2 fused; img out = E2
        skel_pair_kernel<0, 1><<<grid, THREADS, 0, stream>>>(
            yp, y_true, ping, S, zc, nullptr, nullptr, nullptr, 0);

        float* bufs[2] = {ping, pong};
        for (int j = 0; j < 7; ++j) {         // iters 3-16 (7 pairs)
            const float* sA = bufs[j & 1];
            float* oimg = (j < 6) ? bufs[(j + 1) & 1] : nullptr;
            if (j < 6)
                skel_pair_kernel<0, 0><<<grid, THREADS, 0, stream>>>(
                    sA, nullptr, oimg, S, zc, nullptr, nullptr, nullptr, 0);
            else
                skel_pair_kernel<1, 0><<<grid, THREADS, 0, stream>>>(
                    sA, nullptr, oimg, S, zc, y_true, yp, part, 3);
        }
    } else {
        // sequential fallback: one skeleton stream (4 vols) at a time
        float* ping = yp + NB4;
        float* pong = ping + NB4;
        float* Sp   = pong + NB4;
        float* St   = Sp + NB4;
        const int zc = 4;                // zlen 32 -> 512 blocks
        dim3 grid(NW / TX, NH / TY, zc * 4);

        auto run = [&](const float* x, float* S, const float* other, int offBase) {
            skel_pair_kernel<0, 1><<<grid, THREADS, 0, stream>>>(
                x, nullptr, ping, S, zc, nullptr, nullptr, nullptr, 0);
            float* bufs[2] = {ping, pong};
            for (int j = 0; j < 7; ++j) {
                const float* sA = bufs[j & 1];
                float* oimg = (j < 6) ? bufs[(j + 1) & 1] : nullptr;
                if (j < 6)
                    skel_pair_kernel<0, 0><<<grid, THREADS, 0, stream>>>(
                        sA, nullptr, oimg, S, zc, nullptr, nullptr, nullptr, 0);
                else
                    skel_pair_kernel<1, 0><<<grid, THREADS, 0, stream>>>(
                        sA, nullptr, oimg, S, zc, other, nullptr, part, offBase);
            }
        };
        run(yp, Sp, y_true, 3);
        run(y_true, St, yp, 5);
    }

    finalize_kernel<<<1, THREADS, 0, stream>>>(part, out);
}

// Round 11
// 883.059 us; speedup vs baseline: 4.5682x; 4.5682x over previous
//
#include <hip/hip_runtime.h>
#include <cmath>

// Volume: [B=4, C=1, D=128, H=128, W=128] fp32
#define NB 4
#define ND 128
#define NH 128
#define NW 128
#define NVOL_VOX (ND * NH * NW)    // 2097152 per volume
#define NVOX (NB * NVOL_VOX)       // 8388608 (4 volumes)

#define THREADS 256
#define TX 32
#define TY 16
// FINAL CONFIG (= round-9 verified best, 886.6us total / 105.8us per skel dispatch).
// Occupancy levers are DEAD on this toolchain: launch_bounds(256,4) [R2],
// waves_per_eu(4,8) [R7], waves_per_eu(4,4) [R10] ALL squeeze to 64 VGPR ->
// ~1-2.3 GB/dispatch scratch spill (pipeline needs ~115 VGPR). (256,2) -> 112-116
// VGPR, no spill, 2 blocks/CU. Time scales with total block-steps (R0 vs R3), so
// zc=2 (74 steps, minimal z-halo). srcS staging removed (R8: src neighbors per-lane
// global prefetch, 2 steps ahead). x-halo LDS reads are neighbor-f4 b128 (R9).
// Raw s_barrier + lgkmcnt(0) only (R6): global prefetches stay in flight.
// Residual gap (~1400cy/step of 3432) is barrier dependency skew; the 2-slice-per-
// barrier rewrite exceeds both the 64KB LDS limit (INIT) and 128-VGPR budget.
#define SSTR 10
#define RSTR 10
#define ZS4 ((NH * NW) >> 2)       // 4096 f4 per z-slice

#define INFF __builtin_huge_valf()

// barrier that orders LDS only: do NOT drain vmcnt (global prefetches stay in flight)
#define LDS_BARRIER()  do {                                   \
    asm volatile("s_waitcnt lgkmcnt(0)" ::: "memory");        \
    __builtin_amdgcn_s_barrier();                             \
    __builtin_amdgcn_sched_barrier(0);                        \
} while (0)

__device__ __forceinline__ float4 f4min(float4 a, float4 b) {
    return make_float4(fminf(a.x, b.x), fminf(a.y, b.y), fminf(a.z, b.z), fminf(a.w, b.w));
}
__device__ __forceinline__ float4 f4max(float4 a, float4 b) {
    return make_float4(fmaxf(a.x, b.x), fmaxf(a.y, b.y), fmaxf(a.z, b.z), fmaxf(a.w, b.w));
}
__device__ __forceinline__ float4 f4relu_sub(float4 a, float4 b) {
    return make_float4(fmaxf(a.x - b.x, 0.f), fmaxf(a.y - b.y, 0.f),
                       fmaxf(a.z - b.z, 0.f), fmaxf(a.w - b.w, 0.f));
}
// x-window ops with scalar boundary floats
__device__ __forceinline__ float4 f4winmin_s(float lfw, float4 cc, float rtx) {
    float4 o;
    o.x = fminf(fminf(lfw, cc.x), cc.y);
    o.y = fminf(fminf(cc.x, cc.y), cc.z);
    o.z = fminf(fminf(cc.y, cc.z), cc.w);
    o.w = fminf(fminf(cc.z, cc.w), rtx);
    return o;
}
__device__ __forceinline__ float4 f4winmax_s(float lfw, float4 cc, float rtx) {
    float4 o;
    o.x = fmaxf(fmaxf(lfw, cc.x), cc.y);
    o.y = fmaxf(fmaxf(cc.x, cc.y), cc.z);
    o.z = fmaxf(fmaxf(cc.y, cc.z), cc.w);
    o.w = fmaxf(fmaxf(cc.z, cc.w), rtx);
    return o;
}

__device__ __forceinline__ float block_reduce(float v, float* sbuf) {
    for (int off = 32; off > 0; off >>= 1) v += __shfl_down(v, off, 64);
    int lane = threadIdx.x & 63;
    int wid  = threadIdx.x >> 6;
    if (lane == 0) sbuf[wid] = v;
    __syncthreads();
    float r = 0.f;
    if (wid == 0) {
        r = (lane < (int)(blockDim.x >> 6)) ? sbuf[lane] : 0.f;
        for (int off = 8; off > 0; off >>= 1) r += __shfl_down(r, off, 64);
    }
    __syncthreads();
    return r;
}

// ---------------------------------------------------------------------------
// sigmoid + dice partials
// ---------------------------------------------------------------------------
#define SIG_BLOCKS 1024
__global__ void sigmoid_reduce_kernel(const float4* __restrict__ logits,
                                      const float4* __restrict__ yt,
                                      float4* __restrict__ yp,
                                      float* __restrict__ part) {
    __shared__ float sbuf[THREADS / 64];
    const int n4 = NVOX / 4;
    float sp = 0.f, st = 0.f, stp = 0.f;
    for (int i = blockIdx.x * blockDim.x + threadIdx.x; i < n4;
         i += gridDim.x * blockDim.x) {
        float4 l = logits[i];
        float4 t = yt[i];
        float4 p;
        p.x = 1.f / (1.f + expf(-l.x));
        p.y = 1.f / (1.f + expf(-l.y));
        p.z = 1.f / (1.f + expf(-l.z));
        p.w = 1.f / (1.f + expf(-l.w));
        yp[i] = p;
        sp  += p.x + p.y + p.z + p.w;
        st  += t.x + t.y + t.z + t.w;
        stp += t.x * p.x + t.y * p.y + t.z * p.z + t.w * p.w;
    }
    float a = block_reduce(sp, sbuf);
    float b = block_reduce(st, sbuf);
    float c = block_reduce(stp, sbuf);
    if (threadIdx.x == 0) {
        part[blockIdx.x]        = a;
        part[1024 + blockIdx.x] = b;
        part[2048 + blockIdx.x] = c;
    }
}

// ---------------------------------------------------------------------------
// Fused skeleton kernel (pair of iterations; INIT also folds the init step).
// ---------------------------------------------------------------------------
template <int RED, int INIT>
__global__ __launch_bounds__(256, 2)
void skel_pair_kernel(const float* __restrict__ srcA, const float* __restrict__ srcB,
                      float* __restrict__ imgOut, float* __restrict__ skel,
                      int zchunks,
                      const float* __restrict__ othA, const float* __restrict__ othB,
                      float* __restrict__ part, int offBase) {
    // per-slice f4 counts (srcS removed: src neighbors come from global prefetch)
    constexpr int ZE1  = 22 * SSTR;
    constexpr int ZE2  = 20 * SSTR;
    constexpr int ZE3  = 18 * SSTR;
    constexpr int ZRX  = 18 * RSTR;
    // +2: one f4 pad at each end so the ±1-f4 halo reads stay inside smem
    constexpr int NTOT = 2 + 2 * (ZE1 + ZE2 + ZE3 + 2 * ZRX)
                           + (INIT ? 2 * ZRX : 0);
    __shared__ float4 smem[NTOT];
    float4* const e1S  = smem + 1;
    float4* const e2S  = e1S + 2 * ZE1;
    float4* const e3S  = e2S + 2 * ZE2;
    float4* const rxAS = e3S + 2 * ZE3;
    float4* const rxBS = rxAS + 2 * ZRX;
    float4* const rxCS = rxBS + 2 * ZRX;   // only valid for INIT

    const float4 INF4  = make_float4(INFF, INFF, INFF, INFF);
    const float4 MINF4 = make_float4(-INFF, -INFF, -INFF, -INFF);
    const float4 ZERO4 = make_float4(0.f, 0.f, 0.f, 0.f);

    const int zlen  = ND / zchunks;
    const int v     = blockIdx.z / zchunks;
    const int chunk = blockIdx.z - v * zchunks;
    const int z0    = chunk * zlen;
    const int tx0   = blockIdx.x * TX;
    const int ty0   = blockIdx.y * TY;
    const int tid   = threadIdx.x;

    const float* src = srcB ? (v < 4 ? srcA + (size_t)v * NVOL_VOX
                                     : srcB + (size_t)(v - 4) * NVOL_VOX)
                            : srcA + (size_t)v * NVOL_VOX;
    const float4* src4 = (const float4*)src;
    const float*  srcf = src;
    float4* img4 = imgOut ? (float4*)(imgOut + (size_t)v * NVOL_VOX) : nullptr;
    float4* skl4 = (float4*)(skel + (size_t)v * NVOL_VOX);
    const float4* oth4 = nullptr;
    if (RED) {
        const float* oth = othB ? (v < 4 ? othA + (size_t)v * NVOL_VOX
                                         : othB + (size_t)(v - 4) * NVOL_VOX)
                                : othA + (size_t)v * NVOL_VOX;
        oth4 = (const float4*)oth;
    }

    const int fy = tid / 10, qx = tid - (tid / 10) * 10;   // rows 0..23, cols 0..9
    const bool tOK = tid < 240;
    const bool aE1 = tOK && fy >= 1 && fy < 23;
    const bool aE2 = tOK && fy >= 2 && fy < 22;
    const bool aE3 = tOK && fy >= 3 && fy < 21;
    const bool aRx = aE3 && qx >= 1 && qx < 9;
    const bool aC  = tOK && fy >= 4 && fy < 20 && qx >= 1 && qx < 9;
    const bool qxL = (qx == 0);
    const bool qxR = (qx == 9);
    const int gy = ty0 + fy - 4;
    const int gx4 = tx0 + (qx - 1) * 4;
    const bool xOK = tOK && (unsigned)gx4 < NW;
    const bool gOK = xOK && (unsigned)gy < NH;
    const bool upOK = xOK && (unsigned)(gy - 1) < NH;
    const bool dnOK = xOK && (unsigned)(gy + 1) < NH;
    const bool lfOK = gOK && !qxL && (gx4 - 1) >= 0;
    const bool rtOK = gOK && !qxR && (gx4 + 4) < NW;
    const int colBase = gOK ? ((gy * NW + gx4) >> 2) : 0;
    const int colUp   = upOK ? (((gy - 1) * NW + gx4) >> 2) : 0;
    const int colDn   = dnOK ? (((gy + 1) * NW + gx4) >> 2) : 0;
    const int lfIdx   = lfOK ? (gy * NW + gx4 - 1) : 0;
    const int rtIdx   = rtOK ? (gy * NW + gx4 + 4) : 0;
    const int iE1  = (fy - 1) * SSTR + qx;
    const int iE2  = (fy - 2) * SSTR + qx;
    const int iE3  = (fy - 3) * SSTR + qx;
    const int iRx  = (fy - 3) * RSTR + (qx - 1);

    // src register rotation (6 deep): srcF[(u+1)%6]=zL+1 (prefetch), [u%6]=zL,
    // [(u+5)%6]=zL-1, [(u+4)%6]=zL-2, [(u+2)%6]=zL-4 (INIT d0).
    // y-neighbor/x-halo prefetch (3 deep): write slot (u+1)%3 (slice zL+1),
    // consume slot (u+2)%3 (slice zL-1) in E1.
    float4 srcF[6], yupF[3], ydnF[3];
    float  lfwF[3], rtxF[3];
    float4 e1F[6], e2F[6], e3F[2], rxAF[2], rxBF[2], mxyAF[3], mxyBF[3], dAF[2];
    float4 sklF[6], othF[6];
    float4 rxCF[2], mxyCF[3], d0F[3];
#pragma unroll
    for (int i = 0; i < 6; ++i) srcF[i] = INF4;
#pragma unroll
    for (int i = 0; i < 3; ++i) { yupF[i] = INF4; ydnF[i] = INF4; lfwF[i] = INFF; rtxF[i] = INFF; }
#pragma unroll
    for (int i = 0; i < 6; ++i) { e1F[i] = INF4; e2F[i] = INF4; sklF[i] = ZERO4; othF[i] = ZERO4; }
    e3F[0] = e3F[1] = INF4;
    rxAF[0] = rxAF[1] = MINF4;
    rxBF[0] = rxBF[1] = MINF4;
    rxCF[0] = rxCF[1] = MINF4;
    mxyAF[0] = mxyAF[1] = mxyAF[2] = MINF4;
    mxyBF[0] = mxyBF[1] = mxyBF[2] = MINF4;
    mxyCF[0] = mxyCF[1] = mxyCF[2] = MINF4;
    dAF[0] = dAF[1] = ZERO4;
    d0F[0] = d0F[1] = d0F[2] = ZERO4;

    float accS = 0.f, accSO = 0.f;
    const int NSTEP = zlen + 10;

    {   // prologue: own slice z0-4 -> srcF[0]; neighbor slices z0-5 -> slot 2,
        // z0-4 -> slot 0 (consumed by E1 at steps 0,1)
        const int zB = z0 - 4, zA = z0 - 5;
        if ((unsigned)zB < ND && gOK) srcF[0] = src4[zB * ZS4 + colBase];
        if ((unsigned)zA < ND) {
            if (upOK) yupF[2] = src4[zA * ZS4 + colUp];
            if (dnOK) ydnF[2] = src4[zA * ZS4 + colDn];
            if (lfOK) lfwF[2] = srcf[zA * (NH * NW) + lfIdx];
            if (rtOK) rtxF[2] = srcf[zA * (NH * NW) + rtIdx];
        }
        if ((unsigned)zB < ND) {
            if (upOK) yupF[0] = src4[zB * ZS4 + colUp];
            if (dnOK) ydnF[0] = src4[zB * ZS4 + colDn];
            if (lfOK) lfwF[0] = srcf[zB * (NH * NW) + lfIdx];
            if (rtOK) rtxF[0] = srcf[zB * (NH * NW) + rtIdx];
        }
    }

    for (int sb = 0; sb < NSTEP; sb += 6) {
#pragma unroll
        for (int u = 0; u < 6; ++u) {
            if (sb + u >= NSTEP) break;            // uniform exit at exact step count
            const int zL = z0 - 4 + (sb + u);
            const int sl  = u & 1;
            const int slp = sl ^ 1;

            {   // prefetch slice zL+1: own f4 + y-neighbor f4s + x-halo scalars
                const int zN = zL + 1;
                const bool zOK = (unsigned)zN < ND && zN < z0 + zlen + 4;
                float4 vv = INF4, vu = INF4, vd = INF4;
                float lf = INFF, rt = INFF;
                if (zOK) {
                    if (gOK)  vv = src4[zN * ZS4 + colBase];
                    if (upOK) vu = src4[zN * ZS4 + colUp];
                    if (dnOK) vd = src4[zN * ZS4 + colDn];
                    if (lfOK) lf = srcf[zN * (NH * NW) + lfIdx];
                    if (rtOK) rt = srcf[zN * (NH * NW) + rtIdx];
                }
                srcF[(u + 1) % 6] = vv;
                yupF[(u + 1) % 3] = vu;
                ydnF[(u + 1) % 3] = vd;
                lfwF[(u + 1) % 3] = lf;
                rtxF[(u + 1) % 3] = rt;
            }
            if (!INIT) {   // prefetch skel/oth for OUT 3 steps ahead (z = zL-3)
                const int zp = zL - 3;
                const bool pOK = aC && zp >= z0 && zp < z0 + zlen;
                float4 sv = ZERO4;
                if (pOK) sv = skl4[zp * ZS4 + colBase];
                sklF[u] = sv;
                if (RED) {
                    float4 ov = ZERO4;
                    if (pOK) ov = oth4[zp * ZS4 + colBase];
                    othF[u] = ov;
                }
            }
            {   // E1(zL-1) — all inputs from registers (prefetched 2 steps ago)
                const int z = zL - 1;
                float4 vv = INF4;
                if (aE1 && (unsigned)z < ND) {
                    float4 cc = srcF[(u + 5) % 6];                       // zL-1
                    float4 zm = f4min(srcF[(u + 4) % 6], srcF[u % 6]);   // zL-2, zL
                    float lfw = qxL ? INFF : lfwF[(u + 2) % 3];
                    float rtx = qxR ? INFF : rtxF[(u + 2) % 3];
                    float4 xm = f4winmin_s(lfw, cc, rtx);
                    vv = f4min(f4min(xm, yupF[(u + 2) % 3]),
                               f4min(ydnF[(u + 2) % 3], zm));
                }
                e1F[u % 6] = vv;
                if (aE1) e1S[sl * ZE1 + iE1] = vv;
            }
            {   // E2(zL-2) — img output  (x-halo via neighbor-f4 b128)
                const int z = zL - 2;
                float4 vv = INF4;
                if (aE2) {
                    const float4* S = e1S + slp * ZE1;
                    float4 lf4 = S[iE1 - 1];
                    float4 rt4 = S[iE1 + 1];
                    float lfw = qxL ? INFF : lf4.w;
                    float rtx = qxR ? INFF : rt4.x;
                    float4 xm = f4winmin_s(lfw, e1F[(u + 5) % 6], rtx);
                    vv = f4min(f4min(xm, S[iE1 - SSTR]),
                               f4min(S[iE1 + SSTR],
                                     f4min(e1F[(u + 4) % 6], e1F[u % 6])));
                    e2S[sl * ZE2 + iE2] = vv;
                    if (img4 && aC && z >= z0 && z < z0 + zlen)
                        img4[z * ZS4 + colBase] = vv;
                }
                e2F[u % 6] = vv;
            }
            {   // E3(zL-3)  (x-halo via neighbor-f4 b128)
                float4 vv = INF4;
                if (aE3) {
                    const float4* S = e2S + slp * ZE2;
                    float4 lf4 = S[iE2 - 1];
                    float4 rt4 = S[iE2 + 1];
                    float lfw = qxL ? INFF : lf4.w;
                    float rtx = qxR ? INFF : rt4.x;
                    float4 xm = f4winmin_s(lfw, e2F[(u + 5) % 6], rtx);
                    vv = f4min(f4min(xm, S[iE2 - SSTR]),
                               f4min(S[iE2 + SSTR],
                                     f4min(e2F[(u + 4) % 6], e2F[u % 6])));
                    e3S[sl * ZE3 + iE3] = vv;
                }
                e3F[u % 2] = vv;
            }
            {   // rxA(zL-3), rxB(zL-4), [INIT] rxC(zL-2)  (halos via neighbor-f4 b128)
                float4 ra = MINF4, rb = MINF4, rc = MINF4;
                if (aRx) {
                    const float4* A4 = e2S + slp * ZE2;
                    const float4* B4 = e3S + slp * ZE3;
                    float4 aL = A4[iE2 - 1], aR = A4[iE2 + 1];
                    float4 bL = B4[iE3 - 1], bR = B4[iE3 + 1];
                    ra = f4winmax_s(aL.w, e2F[(u + 5) % 6], aR.x);
                    rb = f4winmax_s(bL.w, e3F[(u + 1) % 2], bR.x);
                    rxAS[sl * ZRX + iRx] = ra;
                    rxBS[sl * ZRX + iRx] = rb;
                    if (INIT) {
                        const float4* C4 = e1S + slp * ZE1;
                        float4 cL = C4[iE1 - 1], cR = C4[iE1 + 1];
                        rc = f4winmax_s(cL.w, e1F[(u + 5) % 6], cR.x);
                        rxCS[sl * ZRX + iRx] = rc;
                    }
                }
                float4 mA = MINF4, mB = MINF4, mC = MINF4;
                if (aC) {
                    mA = f4max(f4max(rxAF[(u + 1) % 2], rxAS[slp * ZRX + iRx - RSTR]),
                               rxAS[slp * ZRX + iRx + RSTR]);
                    mB = f4max(f4max(rxBF[(u + 1) % 2], rxBS[slp * ZRX + iRx - RSTR]),
                               rxBS[slp * ZRX + iRx + RSTR]);
                    if (INIT)
                        mC = f4max(f4max(rxCF[(u + 1) % 2], rxCS[slp * ZRX + iRx - RSTR]),
                                   rxCS[slp * ZRX + iRx + RSTR]);
                }
                rxAF[u % 2] = ra;
                rxBF[u % 2] = rb;
                mxyAF[u % 3] = mA;
                mxyBF[u % 3] = mB;
                if (INIT) { rxCF[u % 2] = rc; mxyCF[u % 3] = mC; }
            }
            if (INIT) {   // d0(zL-4) = relu(src(zL-4) - dilate(E1)(zL-4))
                float4 dilC = f4max(f4max(mxyCF[0], mxyCF[1]), mxyCF[2]);
                d0F[u % 3] = f4relu_sub(srcF[(u + 2) % 6], dilC);
            }
            {   // dA(zL-5) = relu(E1(zL-5) - dilA)
                float4 dilA = f4max(f4max(mxyAF[0], mxyAF[1]), mxyAF[2]);
                dAF[u % 2] = f4relu_sub(e1F[(u + 2) % 6], dilA);
            }
            {   // OUT(zL-6)
                const int z = zL - 6;
                if (aC && z >= z0 && z < z0 + zlen) {
                    float4 dilB = f4max(f4max(mxyBF[0], mxyBF[1]), mxyBF[2]);
                    float4 dB = f4relu_sub(e2F[(u + 2) % 6], dilB);
                    float4 da = dAF[(u + 1) % 2];
                    int gi = z * ZS4 + colBase;
                    float4 sv = INIT ? d0F[(u + 1) % 3] : sklF[(u + 3) % 6];
                    float4 s1, s2;
                    s1.x = sv.x + fmaxf(da.x - sv.x * da.x, 0.f);
                    s1.y = sv.y + fmaxf(da.y - sv.y * da.y, 0.f);
                    s1.z = sv.z + fmaxf(da.z - sv.z * da.z, 0.f);
                    s1.w = sv.w + fmaxf(da.w - sv.w * da.w, 0.f);
                    s2.x = s1.x + fmaxf(dB.x - s1.x * dB.x, 0.f);
                    s2.y = s1.y + fmaxf(dB.y - s1.y * dB.y, 0.f);
                    s2.z = s1.z + fmaxf(dB.z - s1.z * dB.z, 0.f);
                    s2.w = s1.w + fmaxf(dB.w - s1.w * dB.w, 0.f);
                    skl4[gi] = s2;
                    if (RED) {
                        accS += s2.x + s2.y + s2.z + s2.w;
                        float4 o = othF[(u + 3) % 6];
                        accSO += s2.x * o.x + s2.y * o.y + s2.z * o.z + s2.w * o.w;
                    }
                }
            }
            LDS_BARRIER();   // raw s_barrier + lgkmcnt(0); global prefetches stay in flight
        }
    }

    if (RED) {
        float* sbuf = (float*)smem;
        float r1 = block_reduce(accS, sbuf);
        float r2 = block_reduce(accSO, sbuf);
        if (tid == 0) {
            int halfSel = (othB && v >= 4) ? 1 : 0;
            int A = (offBase + 2 * halfSel) * 1024;
            int zslot = chunk + zchunks * (v & 3);
            int bid = blockIdx.x + 4 * (blockIdx.y + 8 * zslot);
            part[A + bid] = r1;
            part[A + 1024 + bid] = r2;
        }
    }
}

// ---------------------------------------------------------------------------
// finalize: sum 7 partial arrays (1024 each) and compute the loss scalar
// ---------------------------------------------------------------------------
__global__ void finalize_kernel(const float* __restrict__ part, float* __restrict__ out) {
    __shared__ float sbuf[THREADS / 64];
    float s[7];
#pragma unroll
    for (int k = 0; k < 7; ++k) {
        float local = 0.f;
        for (int i = threadIdx.x; i < 1024; i += THREADS) local += part[k * 1024 + i];
        s[k] = block_reduce(local, sbuf);
    }
    if (threadIdx.x == 0) {
        const float smooth = 1.0f;
        const float alpha = 0.3f;
        float dice = 1.f - (2.f * s[2] + smooth) / (s[1] + s[0] + smooth);
        float tprec = (s[4] + smooth) / (s[3] + smooth);
        float tsens = (s[6] + smooth) / (s[5] + smooth);
        float cl = 1.f - 2.f * (tprec * tsens) / (tprec + tsens);
        out[0] = (1.f - alpha) * dice + alpha * cl;
    }
}

// ---------------------------------------------------------------------------
extern "C" void kernel_launch(void* const* d_in, const int* in_sizes, int n_in,
                              void* d_out, int out_size, void* d_ws, size_t ws_size,
                              hipStream_t stream) {
    const float* y_pred = (const float*)d_in[0];
    const float* y_true = (const float*)d_in[1];
    float* out = (float*)d_out;

    char* ws = (char*)d_ws;
    float* part = (float*)ws;                 // 7 * 1024 floats
    float* yp = (float*)(ws + 32768);
    const size_t NB4 = (size_t)NVOX;
    const size_t need_batched = 32768 + 7 * NB4 * sizeof(float);

    hipMemsetAsync(part, 0, 7 * 1024 * sizeof(float), stream);
    sigmoid_reduce_kernel<<<SIG_BLOCKS, THREADS, 0, stream>>>(
        (const float4*)y_pred, (const float4*)y_true, (float4*)yp, part);

    if (ws_size >= need_batched) {
        // batched: both skeletons (8 volumes) per dispatch
        float* ping = yp + NB4;          // 8-vol
        float* pong = ping + 2 * NB4;    // 8-vol
        float* S    = pong + 2 * NB4;    // 8-vol
        const int zc = 2;                // zlen 64 -> 512 blocks (minimal z-halo)
        dim3 grid(NW / TX, NH / TY, zc * 8);   // 4 x 8 x 16 = 512

        // init + iters 1-2 fused; img out = E2
        skel_pair_kernel<0, 1><<<grid, THREADS, 0, stream>>>(
            yp, y_true, ping, S, zc, nullptr, nullptr, nullptr, 0);

        float* bufs[2] = {ping, pong};
        for (int j = 0; j < 7; ++j) {         // iters 3-16 (7 pairs)
            const float* sA = bufs[j & 1];
            float* oimg = (j < 6) ? bufs[(j + 1) & 1] : nullptr;
            if (j < 6)
                skel_pair_kernel<0, 0><<<grid, THREADS, 0, stream>>>(
                    sA, nullptr, oimg, S, zc, nullptr, nullptr, nullptr, 0);
            else
                skel_pair_kernel<1, 0><<<grid, THREADS, 0, stream>>>(
                    sA, nullptr, oimg, S, zc, y_true, yp, part, 3);
        }
    } else {
        // sequential fallback: one skeleton stream (4 vols) at a time
        float* ping = yp + NB4;
        float* pong = ping + NB4;
        float* Sp   = pong + NB4;
        float* St   = Sp + NB4;
        const int zc = 4;                // zlen 32 -> 512 blocks
        dim3 grid(NW / TX, NH / TY, zc * 4);

        auto run = [&](const float* x, float* S, const float* other, int offBase) {
            skel_pair_kernel<0, 1><<<grid, THREADS, 0, stream>>>(
                x, nullptr, ping, S, zc, nullptr, nullptr, nullptr, 0);
            float* bufs[2] = {ping, pong};
            for (int j = 0; j < 7; ++j) {
                const float* sA = bufs[j & 1];
                float* oimg = (j < 6) ? bufs[(j + 1) & 1] : nullptr;
                if (j < 6)
                    skel_pair_kernel<0, 0><<<grid, THREADS, 0, stream>>>(
                        sA, nullptr, oimg, S, zc, nullptr, nullptr, nullptr, 0);
                else
                    skel_pair_kernel<1, 0><<<grid, THREADS, 0, stream>>>(
                        sA, nullptr, oimg, S, zc, other, nullptr, part, offBase);
            }
        };
        run(yp, Sp, y_true, 3);
        run(y_true, St, yp, 5);
    }

    finalize_kernel<<<1, THREADS, 0, stream>>>(part, out);
}